// Round 18
// baseline (278.672 us; speedup 1.0000x reference)
//
#include <hip/hip_runtime.h>
#include <hip/hip_cooperative_groups.h>

namespace cg = cooperative_groups;

// GaussianKDE via f16 MFMA — COOPERATIVE MEGA-KERNEL: prep -> grid.sync ->
// r12-proven main body (barrier-free, B direct from L2, temporal wave skew,
// burst-separated MFMA/VALU; 40.7us, VGPR 64, no spill) -> grid.sync ->
// fused reduce (1 wave/q, 64-lane butterfly over splits). Eliminates 2
// launch gaps + reduce dispatch (~14us tail -> ~8us). Grid 1024x256 = exactly
// 4 blocks/CU co-resident (VGPR 64, LDS 3.6KB, 16 waves/CU).
// Runtime-guarded: falls back to the proven 3-kernel champion path if
// cooperative launch is unavailable or errors.
// CLOSED DEAD ENDS (counter-confirmed): deeper reg prefetch (spill,
// r6/r8/r11/r14), >1024 blocks (L2 thrash, r4/r9/r13), per-block threadfence
// reduction (L2 flush, r15), producer/consumer waves (barrier serialization,
// r17), 32x32 MFMA (register arithmetic: 143 > 128 cap).
// estimate[q] = (norm/N) * exp2(cf2_q) * sum_n exp2(dot2(q,n)) * ecx_n
//   dot2 = sum_k (log2e * f_qk) * x_nk   (f16 MFMA, fp32 accum, C=0)
//   cf2  = -0.5*log2e*||f_q||^2 (fp32),  ecx = exp2(-0.5*log2e*||x_n||^2)
// xhp is f16 in MFMA-FRAGMENT ORDER; unit = 32 rows = 2048 halves = 4
// coalesced 1KB dwordx4 loads per wave. Per-XCD working set 852 KB -> L2.

#define QCNT 4096
#define NCNT 50000
#define DDIM 64

// fast path (r12 geometry)
#define SPLITS 64
#define NPB 832             // 13*64; SPLITS*NPB = 53248 >= 50000 (padded)
#define NROWS (SPLITS * NPB)
#define NUNITS 26           // units of 32 rows per split
#define QTILES (QCNT / 256) // 16
#define SPLIT_HALVES (NPB * DDIM)   // 53248 f16 per split slice
#define XTASKS (NROWS * 8)          // 425984 = 1024 * 416
#define XPB (XTASKS / 1024)         // 416 x-prep tasks per block

// fallback (round-2 proven path)
#define FSPLITS 32
#define FNPB 1563
#define FNITERS 25
#define BN 64

typedef _Float16 half8_t __attribute__((ext_vector_type(8)));
typedef float float4_t __attribute__((ext_vector_type(4)));

#define K2F 1.44269504088896340f   // log2(e)
#define KC2 -0.72134752044448169f  // -0.5*log2(e)

// ---- shared device helpers (used by mega + standalone paths) -------------

__device__ __forceinline__ void prep_f_row(const float* features,
                                           const float* bw,
                                           _Float16* fh, float* cf2,
                                           int q, int lane) {
    const float* frow = features + q * DDIM;
    float acc = 0.f;
#pragma unroll
    for (int k = 0; k < DDIM; ++k)
        acc = fmaf(frow[k], bw[k * DDIM + lane], acc);
    fh[(size_t)q * DDIM + lane] = (_Float16)(K2F * acc);
    float s = acc * acc;
#pragma unroll
    for (int m = 1; m < 64; m <<= 1) s += __shfl_xor(s, m, 64);
    if (lane == 0) cf2[q] = KC2 * s;
}

__device__ __forceinline__ void prep_x_task(const float* dataset,
                                            _Float16* xhp, float* ecxg,
                                            int t) {
    const int row = t >> 3;
    const int c = t & 7;                  // 8-half chunk = k [c*8, c*8+8)
    if (row >= NROWS) return;
    float4_t v0 = {0.f, 0.f, 0.f, 0.f}, v1 = {0.f, 0.f, 0.f, 0.f};
    if (row < NCNT) {
        const float4_t* src = (const float4_t*)(dataset + (size_t)row * DDIM + c * 8);
        v0 = src[0]; v1 = src[1];
    }
    float s = v0[0]*v0[0] + v0[1]*v0[1] + v0[2]*v0[2] + v0[3]*v0[3]
            + v1[0]*v1[0] + v1[1]*v1[1] + v1[2]*v1[2] + v1[3]*v1[3];
    s += __shfl_xor(s, 1, 64);
    s += __shfl_xor(s, 2, 64);
    s += __shfl_xor(s, 4, 64);
    if (c == 0) ecxg[row] = (row < NCNT) ? __builtin_amdgcn_exp2f(KC2 * s) : 0.f;
    half8_t h;
    h[0] = (_Float16)v0[0]; h[1] = (_Float16)v0[1];
    h[2] = (_Float16)v0[2]; h[3] = (_Float16)v0[3];
    h[4] = (_Float16)v1[0]; h[5] = (_Float16)v1[1];
    h[6] = (_Float16)v1[2]; h[7] = (_Float16)v1[3];
    // fragment-order address: row -> (split, it, nt, l15); c -> (f, lh)
    const int split = row / NPB;
    const int nr = row - split * NPB;
    const int it = nr >> 6;
    const int brow = nr & 63;
    const int nt = brow >> 4;
    const int l15 = brow & 15;
    const int f = c >> 2;
    const int lh = c & 3;
    const int lane = lh * 16 + l15;
    const size_t base = ((((size_t)split * 13 + it) * 4 + nt) * 2 + f) * 512;
    *(half8_t*)(xhp + base + lane * 8) = h;
}

// ---- r12-proven main body as a device function ---------------------------
__device__ __forceinline__ void main_body(const _Float16* fh,
                                          const float* ecxg,
                                          const _Float16* xhp,
                                          float* partial,
                                          float* lecx,       // [NPB] LDS
                                          int bid, int tid) {
    const int lane = tid & 63;
    const int w = tid >> 6;
    const int l15 = lane & 15;
    const int lh = lane >> 4;

    // bijective XCD swizzle (r3-proven): 1024 = 8 xcd x 8 splits x 16 qtiles
    const int xcd = bid & 7;
    const int j = bid >> 3;                 // 0..127
    const int split = xcd * 8 + (j & 7);    // 0..63
    const int qtile = j >> 3;               // 0..15

    const int qbase = qtile * 256 + w * 64; // wave owns 64 q-rows

    // A fragments resident in VGPRs: lane l -> row qt*16+l15, k = kt*32+lh*8
    half8_t a[4][2];
#pragma unroll
    for (int qt = 0; qt < 4; ++qt)
#pragma unroll
        for (int kt = 0; kt < 2; ++kt)
            a[qt][kt] = *(const half8_t*)(fh + (size_t)(qbase + qt * 16 + l15) * DDIM
                                             + kt * 32 + lh * 8);

    // persistent ecx tile for all iterations
    {
        const float* es = ecxg + (size_t)split * NPB;
        for (int i = tid; i < NPB; i += 256) lecx[i] = es[i];
    }
    __syncthreads();

    // TEMPORAL skew: desynchronize co-resident waves (r10-proven, +13%)
    {
        const int skew = w + ((bid >> 3) & 3);   // 0..6
#pragma unroll 1
        for (int i = 0; i < skew; ++i) __builtin_amdgcn_s_sleep(2);
    }

    const _Float16* bs = xhp + (size_t)split * SPLIT_HALVES + (size_t)lane * 8;

    float sum[4][4];
#pragma unroll
    for (int qt = 0; qt < 4; ++qt)
#pragma unroll
        for (int r = 0; r < 4; ++r) sum[qt][r] = 0.f;

    const float4_t zc = {0.f, 0.f, 0.f, 0.f};   // hoisted zero C quad

#define LOADU(P, u_)                                                          \
    {                                                                         \
        const _Float16* p_ = bs + (size_t)(u_) * 2048;                        \
        P[0][0] = *(const half8_t*)(p_);                                      \
        P[0][1] = *(const half8_t*)(p_ + 512);                                \
        P[1][0] = *(const half8_t*)(p_ + 1024);                               \
        P[1][1] = *(const half8_t*)(p_ + 1536);                               \
    }

#define COMPU(P, u_)                                                          \
    {                                                                         \
        _Pragma("unroll")                                                     \
        for (int s_ = 0; s_ < 2; ++s_) {                                      \
            const float e_ = lecx[(u_) * 32 + s_ * 16 + l15];                 \
            float4_t t0, t1, t2, t3;                                          \
            __builtin_amdgcn_s_setprio(1);                                    \
            t0 = __builtin_amdgcn_mfma_f32_16x16x32_f16(a[0][0], P[s_][0], zc, 0, 0, 0); \
            t1 = __builtin_amdgcn_mfma_f32_16x16x32_f16(a[1][0], P[s_][0], zc, 0, 0, 0); \
            t2 = __builtin_amdgcn_mfma_f32_16x16x32_f16(a[2][0], P[s_][0], zc, 0, 0, 0); \
            t3 = __builtin_amdgcn_mfma_f32_16x16x32_f16(a[3][0], P[s_][0], zc, 0, 0, 0); \
            t0 = __builtin_amdgcn_mfma_f32_16x16x32_f16(a[0][1], P[s_][1], t0, 0, 0, 0); \
            t1 = __builtin_amdgcn_mfma_f32_16x16x32_f16(a[1][1], P[s_][1], t1, 0, 0, 0); \
            t2 = __builtin_amdgcn_mfma_f32_16x16x32_f16(a[2][1], P[s_][1], t2, 0, 0, 0); \
            t3 = __builtin_amdgcn_mfma_f32_16x16x32_f16(a[3][1], P[s_][1], t3, 0, 0, 0); \
            __builtin_amdgcn_s_setprio(0);                                    \
            _Pragma("unroll")                                                 \
            for (int r = 0; r < 4; ++r) {                                     \
                sum[0][r] = fmaf(__builtin_amdgcn_exp2f(t0[r]), e_, sum[0][r]); \
                sum[1][r] = fmaf(__builtin_amdgcn_exp2f(t1[r]), e_, sum[1][r]); \
                sum[2][r] = fmaf(__builtin_amdgcn_exp2f(t2[r]), e_, sum[2][r]); \
                sum[3][r] = fmaf(__builtin_amdgcn_exp2f(t3[r]), e_, sum[3][r]); \
            }                                                                 \
        }                                                                     \
    }

    half8_t bA[2][2], bB[2][2];             // 16 + 16 VGPRs (half-unit each)

    LOADU(bA, 0);
#pragma unroll 1
    for (int u = 0; u < NUNITS; u += 2) {   // u = 0,2,...,24 (NUNITS even)
        LOADU(bB, u + 1);                   // in flight while computing A
        COMPU(bA, u);
        if (u + 2 < NUNITS) LOADU(bA, u + 2);
        COMPU(bB, u + 1);
    }

    // reduce over the 16 n-columns (lanes within each lh group)
#pragma unroll
    for (int qt = 0; qt < 4; ++qt)
#pragma unroll
        for (int r = 0; r < 4; ++r) {
            float s = sum[qt][r];
            s += __shfl_xor(s, 1, 64);
            s += __shfl_xor(s, 2, 64);
            s += __shfl_xor(s, 4, 64);
            s += __shfl_xor(s, 8, 64);
            sum[qt][r] = s;
        }
    if (l15 == 0) {
        float* dst = partial + (size_t)split * QCNT + qbase;
#pragma unroll
        for (int qt = 0; qt < 4; ++qt)
#pragma unroll
            for (int r = 0; r < 4; ++r)
                dst[qt * 16 + lh * 4 + r] = sum[qt][r];   // C row = lh*4 + r
    }
#undef LOADU
#undef COMPU
}

// ---- cooperative mega-kernel: prep -> sync -> main -> sync -> reduce -----
__global__ __launch_bounds__(256, 4)
void kde_mega(const float* __restrict__ features,
              const float* __restrict__ bw,
              const float* __restrict__ dataset,
              const float* __restrict__ norm,
              float* __restrict__ out,
              _Float16* __restrict__ fh,
              float* __restrict__ cf2,
              _Float16* __restrict__ xhp,
              float* __restrict__ ecxg,
              float* __restrict__ partial) {
    __shared__ float lecx[NPB];             // 3.25 KB
    const int tid = threadIdx.x;
    const int bid = blockIdx.x;             // 0..1023
    const int lane = tid & 63;

    // ---- phase 1: prep (1024 blocks cover f-prep + x-prep) ----
    prep_f_row(features, bw, fh, cf2, bid * 4 + (tid >> 6), lane);
    {
        const int tend = (bid + 1) * XPB;
#pragma unroll 1
        for (int t = bid * XPB + tid; t < tend; t += 256)
            prep_x_task(dataset, xhp, ecxg, t);
    }

    cg::this_grid().sync();

    // ---- phase 2: main (r12 champion body) ----
    main_body(fh, ecxg, xhp, partial, lecx, bid, tid);

    cg::this_grid().sync();

    // ---- phase 3: reduce (1 wave per q; lane = split; butterfly) ----
    {
        const int q = bid * 4 + (tid >> 6);     // 4096 waves = 4096 q
        float s = partial[(size_t)lane * QCNT + q];
#pragma unroll
        for (int m = 1; m < 64; m <<= 1) s += __shfl_xor(s, m, 64);
        if (lane == 0)
            out[q] = s * __builtin_amdgcn_exp2f(cf2[q]) * norm[0]
                       * (1.0f / (float)NCNT);
    }
}

// ================= standalone champion path (fallback-1) ==================
#define PREP_F_BLOCKS (QCNT / 4)            // 1024
#define PREP_X_BLOCKS (NROWS * 8 / 256)     // 1664

__global__ void prep_fused(const float* __restrict__ features,
                           const float* __restrict__ bw,
                           const float* __restrict__ dataset,
                           _Float16* __restrict__ fh,
                           float* __restrict__ cf2,
                           _Float16* __restrict__ xhp,
                           float* __restrict__ ecxg) {
    if (blockIdx.x < PREP_F_BLOCKS) {
        prep_f_row(features, bw, fh, cf2,
                   blockIdx.x * 4 + (threadIdx.x >> 6), threadIdx.x & 63);
    } else {
        const int t = (blockIdx.x - PREP_F_BLOCKS) * 256 + threadIdx.x;
        prep_x_task(dataset, xhp, ecxg, t);
    }
}

__global__ __launch_bounds__(256, 4)
void kde_main_fast(const _Float16* __restrict__ fh,
                   const float* __restrict__ ecxg,
                   const _Float16* __restrict__ xhp,
                   float* __restrict__ partial) {
    __shared__ float lecx[NPB];
    main_body(fh, ecxg, xhp, partial, lecx, blockIdx.x, threadIdx.x);
}

// ======================= fallback path (round-2, proven) ==================
__global__ void prep_f_kernel(const float* __restrict__ features,
                              const float* __restrict__ bw,
                              _Float16* __restrict__ fh,
                              float* __restrict__ cf2) {
    const int q = blockIdx.x * (blockDim.x >> 6) + (threadIdx.x >> 6);
    if (q >= QCNT) return;
    prep_f_row(features, bw, fh, cf2, q, threadIdx.x & 63);
}

__global__ void prep_x2_kernel(const float* __restrict__ dataset,
                               float* __restrict__ cx2) {
    const int n = blockIdx.x * blockDim.x + threadIdx.x;
    if (n >= NCNT) return;
    const float4* row = (const float4*)(dataset + (size_t)n * DDIM);
    float s = 0.f;
#pragma unroll
    for (int jq = 0; jq < DDIM / 4; ++jq) {
        float4 v = row[jq];
        s += v.x * v.x + v.y * v.y + v.z * v.z + v.w * v.w;
    }
    cx2[n] = KC2 * s;
}

__global__ __launch_bounds__(256, 2)
void kde_main_fb(const _Float16* __restrict__ fh,
                 const float* __restrict__ cx2,
                 const float* __restrict__ dataset,
                 float* __restrict__ partial) {
    __shared__ __align__(16) _Float16 xt[BN * DDIM];
    const int tid = threadIdx.x;
    const int lane = tid & 63;
    const int w = tid >> 6;
    const int l15 = lane & 15;
    const int lh = lane >> 4;
    const int qbase = blockIdx.x * 256 + w * 64;
    const int nstart = blockIdx.y * FNPB;
    const int nlimit = min(nstart + FNPB, NCNT);

    half8_t a[4][2];
#pragma unroll
    for (int qt = 0; qt < 4; ++qt)
#pragma unroll
        for (int kt = 0; kt < 2; ++kt)
            a[qt][kt] = *(const half8_t*)(fh + (size_t)(qbase + qt * 16 + l15) * DDIM
                                             + kt * 32 + lh * 8);
    float sum[4][4];
#pragma unroll
    for (int qt = 0; qt < 4; ++qt)
#pragma unroll
        for (int r = 0; r < 4; ++r) sum[qt][r] = 0.f;

    const int sn = tid >> 2;
    const int sk = tid & 3;
    const int c0 = (sk * 2) ^ (sn & 7);
    const int c1 = (sk * 2 + 1) ^ (sn & 7);

    for (int it = 0; it < FNITERS; ++it) {
        const int nb = nstart + it * BN;
        __syncthreads();
        {
            const int ng = nb + sn;
            float4_t v0 = {0.f,0.f,0.f,0.f}, v1 = {0.f,0.f,0.f,0.f};
            float4_t v2 = {0.f,0.f,0.f,0.f}, v3 = {0.f,0.f,0.f,0.f};
            if (ng < nlimit) {
                const float4_t* src = (const float4_t*)(dataset + (size_t)ng * DDIM + sk * 16);
                v0 = src[0]; v1 = src[1]; v2 = src[2]; v3 = src[3];
            }
            half8_t h0, h1;
            h0[0]=(_Float16)v0[0]; h0[1]=(_Float16)v0[1]; h0[2]=(_Float16)v0[2]; h0[3]=(_Float16)v0[3];
            h0[4]=(_Float16)v1[0]; h0[5]=(_Float16)v1[1]; h0[6]=(_Float16)v1[2]; h0[7]=(_Float16)v1[3];
            h1[0]=(_Float16)v2[0]; h1[1]=(_Float16)v2[1]; h1[2]=(_Float16)v2[2]; h1[3]=(_Float16)v2[3];
            h1[4]=(_Float16)v3[0]; h1[5]=(_Float16)v3[1]; h1[6]=(_Float16)v3[2]; h1[7]=(_Float16)v3[3];
            *(half8_t*)(xt + sn * DDIM + c0 * 8) = h0;
            *(half8_t*)(xt + sn * DDIM + c1 * 8) = h1;
        }
        __syncthreads();
#pragma unroll
        for (int nt = 0; nt < 4; ++nt) {
            const int ng = nb + nt * 16 + l15;
            const float c2 = (ng < nlimit) ? cx2[ng] : -1.0e30f;
            const int brow = nt * 16 + l15;
            const half8_t b0 = *(const half8_t*)(xt + brow * DDIM + ((lh ^ (brow & 7)) * 8));
            const half8_t b1 = *(const half8_t*)(xt + brow * DDIM + (((4 + lh) ^ (brow & 7)) * 8));
#pragma unroll
            for (int qt = 0; qt < 4; ++qt) {
                float4_t c = {c2, c2, c2, c2};
                float4_t acc = __builtin_amdgcn_mfma_f32_16x16x32_f16(a[qt][0], b0, c, 0, 0, 0);
                acc = __builtin_amdgcn_mfma_f32_16x16x32_f16(a[qt][1], b1, acc, 0, 0, 0);
#pragma unroll
                for (int r = 0; r < 4; ++r)
                    sum[qt][r] += __builtin_amdgcn_exp2f(acc[r]);
            }
        }
    }
#pragma unroll
    for (int qt = 0; qt < 4; ++qt)
#pragma unroll
        for (int r = 0; r < 4; ++r) {
            float s = sum[qt][r];
            s += __shfl_xor(s, 1, 64);
            s += __shfl_xor(s, 2, 64);
            s += __shfl_xor(s, 4, 64);
            s += __shfl_xor(s, 8, 64);
            sum[qt][r] = s;
        }
    if (l15 == 0) {
        float* dst = partial + (size_t)blockIdx.y * QCNT + qbase;
#pragma unroll
        for (int qt = 0; qt < 4; ++qt)
#pragma unroll
            for (int r = 0; r < 4; ++r)
                dst[qt * 16 + lh * 4 + r] = sum[qt][r];
    }
}

// ---- standalone final reduce --------------------------------------------
__global__ void reduce_kernel(const float* __restrict__ partial,
                              const float* __restrict__ cf2,
                              const float* __restrict__ norm,
                              float* __restrict__ out, int splits) {
    const int t = blockIdx.x * blockDim.x + threadIdx.x;  // 0..16383
    const int q = t >> 2;
    const int sub = t & 3;
    if (q >= QCNT) return;
    const int per = splits >> 2;
    float s = 0.f;
    for (int sp = sub * per; sp < (sub + 1) * per; ++sp)
        s += partial[(size_t)sp * QCNT + q];
    s += __shfl_xor(s, 1, 64);
    s += __shfl_xor(s, 2, 64);
    if (sub == 0)
        out[q] = s * __builtin_amdgcn_exp2f(cf2[q]) * norm[0] * (1.0f / (float)NCNT);
}

extern "C" void kernel_launch(void* const* d_in, const int* in_sizes, int n_in,
                              void* d_out, int out_size, void* d_ws, size_t ws_size,
                              hipStream_t stream) {
    const float* features = (const float*)d_in[0];
    const float* bw       = (const float*)d_in[1];
    const float* dataset  = (const float*)d_in[2];
    const float* norm     = (const float*)d_in[3];
    float* out = (float*)d_out;
    float* ws = (float*)d_ws;

    // fast-path ws layout (floats): xhp 1703936 | fh 131072 | cf2 4096 |
    // ecxg 53248 | partial 262144  => 8.62 MB
    const size_t NEED = (size_t)(1703936 + 131072 + 4096 + 53248 + 262144) * 4;

    if (ws_size >= NEED) {
        _Float16* xhp = (_Float16*)ws;
        _Float16* fh  = (_Float16*)(ws + 1703936);
        float* cf2     = ws + 1703936 + 131072;
        float* ecxg    = cf2 + 4096;
        float* partial = ecxg + 53248;

        int coop = 0, dev = 0;
        hipGetDevice(&dev);
        hipDeviceGetAttribute(&coop, hipDeviceAttributeCooperativeLaunch, dev);

        bool launched = false;
        if (coop) {
            void* kargs[] = {(void*)&features, (void*)&bw, (void*)&dataset,
                             (void*)&norm, (void*)&out, (void*)&fh,
                             (void*)&cf2, (void*)&xhp, (void*)&ecxg,
                             (void*)&partial};
            hipError_t e = hipLaunchCooperativeKernel(
                (void*)kde_mega, dim3(QTILES * SPLITS), dim3(256),
                kargs, 0, stream);
            launched = (e == hipSuccess);
        }
        if (!launched) {
            // champion 3-kernel path (55.0us proven)
            prep_fused<<<PREP_F_BLOCKS + PREP_X_BLOCKS, 256, 0, stream>>>(
                features, bw, dataset, fh, cf2, xhp, ecxg);
            kde_main_fast<<<QTILES * SPLITS, 256, 0, stream>>>(fh, ecxg, xhp, partial);
            reduce_kernel<<<(QCNT * 4) / 256, 256, 0, stream>>>(
                partial, cf2, norm, out, SPLITS);
        }
    } else {
        _Float16* fh = (_Float16*)ws;                 // 131072 floats
        float* cf2     = ws + 131072;
        float* cx2     = ws + 131072 + 4096;
        float* partial = ws + 131072 + 4096 + 50176;  // FSPLITS*QCNT

        prep_f_kernel<<<QCNT / 4, 256, 0, stream>>>(features, bw, fh, cf2);
        prep_x2_kernel<<<(NCNT + 255) / 256, 256, 0, stream>>>(dataset, cx2);
        dim3 grid(QCNT / 256, FSPLITS);
        kde_main_fb<<<grid, 256, 0, stream>>>(fh, cx2, dataset, partial);
        reduce_kernel<<<(QCNT * 4) / 256, 256, 0, stream>>>(partial, cf2, norm, out, FSPLITS);
    }
}

// Round 19
// 56.473 us; speedup vs baseline: 4.9346x; 4.9346x over previous
//
#include <hip/hip_runtime.h>

// GaussianKDE via f16 MFMA — 2-STAGE PIPELINE, SPILL-FREE VARIANT:
// 512-thread blocks, 8 waves x 32 q-rows (halved per-wave state so the
// intra-wave two-stage schedule {MFMA h+1 || exp2 h} fits the register
// budget; launch_bounds(512,2) frees the allocator from the 64-VGPR pin
// that confounded r14). Same 1024 blocks / XCD swizzle / skew / L2-resident
// xhp as the 55.0us champion.
// CLOSED DEAD ENDS (counter-confirmed): deeper reg prefetch at 256thr
// (spill, r6/r8/r9/r11/r14), >1024 blocks (L2 thrash, r4/r9/r13),
// threadfence reduction (L2 flush, r15), producer/consumer waves (barrier
// serialization, r17), grid.sync mega-kernel (cross-XCD coherence, r18).
// estimate[q] = (norm/N) * exp2(cf2_q) * sum_n exp2(dot2(q,n)) * ecx_n
//   dot2 = sum_k (log2e * f_qk) * x_nk   (f16 MFMA, fp32 accum, C=0)
//   cf2  = -0.5*log2e*||f_q||^2 (fp32),  ecx = exp2(-0.5*log2e*||x_n||^2)
// xhp is f16 in MFMA-FRAGMENT ORDER; half-unit = 16 rows = 1024 halves =
// 2 coalesced 1KB dwordx4 loads per wave. Per-XCD working set 852 KB -> L2.

#define QCNT 4096
#define NCNT 50000
#define DDIM 64

// fast path
#define SPLITS 64
#define NPB 832             // 13*64; SPLITS*NPB = 53248 >= 50000 (padded)
#define NROWS (SPLITS * NPB)
#define NHALVES 52          // half-units of 16 rows per split
#define QTILES (QCNT / 256) // 16
#define SPLIT_HALVES (NPB * DDIM)   // 53248 f16 per split slice

// fallback (round-2 proven path)
#define FSPLITS 32
#define FNPB 1563
#define FNITERS 25
#define BN 64

typedef _Float16 half8_t __attribute__((ext_vector_type(8)));
typedef float float4_t __attribute__((ext_vector_type(4)));

#define K2F 1.44269504088896340f   // log2(e)
#define KC2 -0.72134752044448169f  // -0.5*log2(e)

// ---- fused prep: blocks [0,1024) do f-prep; [1024, 2688) do x-prep ------
#define PREP_F_BLOCKS (QCNT / 4)            // 1024
#define PREP_X_BLOCKS (NROWS * 8 / 256)     // 1664

__global__ void prep_fused(const float* __restrict__ features,
                           const float* __restrict__ bw,
                           const float* __restrict__ dataset,
                           _Float16* __restrict__ fh,
                           float* __restrict__ cf2,
                           _Float16* __restrict__ xhp,
                           float* __restrict__ ecxg) {
    if (blockIdx.x < PREP_F_BLOCKS) {
        // f = features@bw; fh = f16(K2*f); cf2 = KC2*||f||^2  (1 wave / q-row)
        const int lane = threadIdx.x & 63;
        const int q = blockIdx.x * 4 + (threadIdx.x >> 6);
        const float* frow = features + q * DDIM;
        float acc = 0.f;
#pragma unroll
        for (int k = 0; k < DDIM; ++k)
            acc = fmaf(frow[k], bw[k * DDIM + lane], acc);
        fh[(size_t)q * DDIM + lane] = (_Float16)(K2F * acc);
        float s = acc * acc;
#pragma unroll
        for (int m = 1; m < 64; m <<= 1) s += __shfl_xor(s, m, 64);
        if (lane == 0) cf2[q] = KC2 * s;
    } else {
        // xhp = f16 dataset in MFMA-fragment order; ecxg = exp2(KC2*||x||^2)
        const int t = (blockIdx.x - PREP_F_BLOCKS) * 256 + threadIdx.x;
        const int row = t >> 3;
        const int c = t & 7;                  // 8-half chunk = k [c*8, c*8+8)
        if (row >= NROWS) return;
        float4_t v0 = {0.f, 0.f, 0.f, 0.f}, v1 = {0.f, 0.f, 0.f, 0.f};
        if (row < NCNT) {
            const float4_t* src = (const float4_t*)(dataset + (size_t)row * DDIM + c * 8);
            v0 = src[0]; v1 = src[1];
        }
        float s = v0[0]*v0[0] + v0[1]*v0[1] + v0[2]*v0[2] + v0[3]*v0[3]
                + v1[0]*v1[0] + v1[1]*v1[1] + v1[2]*v1[2] + v1[3]*v1[3];
        s += __shfl_xor(s, 1, 64);
        s += __shfl_xor(s, 2, 64);
        s += __shfl_xor(s, 4, 64);
        if (c == 0) ecxg[row] = (row < NCNT) ? __builtin_amdgcn_exp2f(KC2 * s) : 0.f;
        half8_t h;
        h[0] = (_Float16)v0[0]; h[1] = (_Float16)v0[1];
        h[2] = (_Float16)v0[2]; h[3] = (_Float16)v0[3];
        h[4] = (_Float16)v1[0]; h[5] = (_Float16)v1[1];
        h[6] = (_Float16)v1[2]; h[7] = (_Float16)v1[3];
        // fragment-order address: row -> (split, half hh, l15); c -> (f, lh)
        const int split = row / NPB;
        const int nr = row - split * NPB;
        const int hh = nr >> 4;               // half-unit 0..51 (16 rows)
        const int l15 = nr & 15;
        const int f = c >> 2;
        const int lh = c & 3;
        const int lane = lh * 16 + l15;
        const size_t base = (((size_t)split * NHALVES + hh) * 2 + f) * 512;
        *(half8_t*)(xhp + base + lane * 8) = h;
    }
}

// ---- main (fast): 8 waves x 32q, intra-wave 2-stage (MFMA h+1 || exp2 h) -
__global__ __launch_bounds__(512, 2)
void kde_main_fast(const _Float16* __restrict__ fh,
                   const float* __restrict__ ecxg,
                   const _Float16* __restrict__ xhp,
                   float* __restrict__ partial) {
    __shared__ float lecx[NPB];             // 3.25 KB, read-only after init

    const int tid = threadIdx.x;
    const int lane = tid & 63;
    const int w = tid >> 6;                 // 0..7
    const int l15 = lane & 15;
    const int lh = lane >> 4;

    // bijective XCD swizzle (r3-proven): 1024 = 8 xcd x 8 splits x 16 qtiles
    const int bid = blockIdx.x;
    const int xcd = bid & 7;
    const int j = bid >> 3;                 // 0..127
    const int split = xcd * 8 + (j & 7);    // 0..63
    const int qtile = j >> 3;               // 0..15

    const int qbase = qtile * 256 + w * 32; // wave owns 32 q-rows

    // A fragments resident in VGPRs: lane l -> row qt*16+l15, k = kt*32+lh*8
    half8_t a[2][2];
#pragma unroll
    for (int qt = 0; qt < 2; ++qt)
#pragma unroll
        for (int kt = 0; kt < 2; ++kt)
            a[qt][kt] = *(const half8_t*)(fh + (size_t)(qbase + qt * 16 + l15) * DDIM
                                             + kt * 32 + lh * 8);

    // persistent ecx tile for all iterations
    {
        const float* es = ecxg + (size_t)split * NPB;
        for (int i = tid; i < NPB; i += 512) lecx[i] = es[i];
    }
    __syncthreads();                        // only barrier in the kernel

    // TEMPORAL skew: desynchronize co-resident waves (r10-proven, +13%)
    {
        const int skew = w + ((bid >> 3) & 3);   // 0..10
#pragma unroll 1
        for (int i = 0; i < skew; ++i) __builtin_amdgcn_s_sleep(2);
    }

    const _Float16* bs = xhp + (size_t)split * SPLIT_HALVES + (size_t)lane * 8;

    float sum[2][4];
#pragma unroll
    for (int qt = 0; qt < 2; ++qt)
#pragma unroll
        for (int r = 0; r < 4; ++r) sum[qt][r] = 0.f;

    const float4_t zc = {0.f, 0.f, 0.f, 0.f};   // hoisted zero C quad

    // half-unit h: 16 rows = 2 x 1KB coalesced dwordx4
#define LOADH(L, h_)                                                          \
    {                                                                         \
        const _Float16* p_ = bs + (size_t)(h_) * 1024;                        \
        L[0] = *(const half8_t*)(p_);                                         \
        L[1] = *(const half8_t*)(p_ + 512);                                   \
    }

    // 4 back-to-back MFMA into the T pair (matrix pipe burst)
#define MFMAH(T, L)                                                           \
    {                                                                         \
        __builtin_amdgcn_s_setprio(1);                                        \
        T[0] = __builtin_amdgcn_mfma_f32_16x16x32_f16(a[0][0], L[0], zc, 0, 0, 0); \
        T[1] = __builtin_amdgcn_mfma_f32_16x16x32_f16(a[1][0], L[0], zc, 0, 0, 0); \
        T[0] = __builtin_amdgcn_mfma_f32_16x16x32_f16(a[0][1], L[1], T[0], 0, 0, 0); \
        T[1] = __builtin_amdgcn_mfma_f32_16x16x32_f16(a[1][1], L[1], T[1], 0, 0, 0); \
        __builtin_amdgcn_s_setprio(0);                                        \
    }

    // 8 exp2 + 8 fma for half h_ (trans/VALU burst)
#define EXPH(T, h_)                                                           \
    {                                                                         \
        const float e_ = lecx[(h_) * 16 + l15];                               \
        _Pragma("unroll")                                                     \
        for (int r = 0; r < 4; ++r) {                                         \
            sum[0][r] = fmaf(__builtin_amdgcn_exp2f(T[0][r]), e_, sum[0][r]); \
            sum[1][r] = fmaf(__builtin_amdgcn_exp2f(T[1][r]), e_, sum[1][r]); \
        }                                                                     \
    }

    half8_t lA[2], lB[2];                   // 8 + 8 VGPRs
    float4_t tA[2], tB[2];                  // 8 + 8 VGPRs

    // prologue: establish invariant {tA = MFMA(h), lB = h+1, lA = h+2}
    LOADH(lA, 0);
    LOADH(lB, 1);
    MFMAH(tA, lA);                          // half 0
    LOADH(lA, 2);

#pragma unroll 1
    for (int h = 0; h < NHALVES - 4; h += 2) {   // h = 0,2,...,46
        MFMAH(tB, lB);                      // half h+1 -> matrix pipe busy
        EXPH(tA, h);                        // half h   -> trans pipe busy
        LOADH(lB, h + 3);
        MFMAH(tA, lA);                      // half h+2
        EXPH(tB, h + 1);
        LOADH(lA, h + 4);
    }
    // exit invariant: tA = MFMA(48), lB = half 49, lA = half 50
    MFMAH(tB, lB);                          // half 49
    EXPH(tA, 48);
    LOADH(lB, 51);
    MFMAH(tA, lA);                          // half 50
    EXPH(tB, 49);
    MFMAH(tB, lB);                          // half 51
    EXPH(tA, 50);
    EXPH(tB, 51);

    // reduce over the 16 n-columns (lanes within each lh group)
#pragma unroll
    for (int qt = 0; qt < 2; ++qt)
#pragma unroll
        for (int r = 0; r < 4; ++r) {
            float s = sum[qt][r];
            s += __shfl_xor(s, 1, 64);
            s += __shfl_xor(s, 2, 64);
            s += __shfl_xor(s, 4, 64);
            s += __shfl_xor(s, 8, 64);
            sum[qt][r] = s;
        }
    if (l15 == 0) {
        float* dst = partial + (size_t)split * QCNT + qbase;
#pragma unroll
        for (int qt = 0; qt < 2; ++qt)
#pragma unroll
            for (int r = 0; r < 4; ++r)
                dst[qt * 16 + lh * 4 + r] = sum[qt][r];   // C row = lh*4 + r
    }
#undef LOADH
#undef MFMAH
#undef EXPH
}

// ======================= fallback path (round-2, proven) ==================
__global__ void prep_f_kernel(const float* __restrict__ features,
                              const float* __restrict__ bw,
                              _Float16* __restrict__ fh,
                              float* __restrict__ cf2) {
    const int lane = threadIdx.x & 63;
    const int q = blockIdx.x * (blockDim.x >> 6) + (threadIdx.x >> 6);
    if (q >= QCNT) return;
    const float* frow = features + q * DDIM;
    float acc = 0.f;
#pragma unroll
    for (int k = 0; k < DDIM; ++k)
        acc = fmaf(frow[k], bw[k * DDIM + lane], acc);
    fh[(size_t)q * DDIM + lane] = (_Float16)(K2F * acc);
    float s = acc * acc;
#pragma unroll
    for (int m = 1; m < 64; m <<= 1) s += __shfl_xor(s, m, 64);
    if (lane == 0) cf2[q] = KC2 * s;
}

__global__ void prep_x2_kernel(const float* __restrict__ dataset,
                               float* __restrict__ cx2) {
    const int n = blockIdx.x * blockDim.x + threadIdx.x;
    if (n >= NCNT) return;
    const float4* row = (const float4*)(dataset + (size_t)n * DDIM);
    float s = 0.f;
#pragma unroll
    for (int jq = 0; jq < DDIM / 4; ++jq) {
        float4 v = row[jq];
        s += v.x * v.x + v.y * v.y + v.z * v.z + v.w * v.w;
    }
    cx2[n] = KC2 * s;
}

__global__ __launch_bounds__(256, 2)
void kde_main_fb(const _Float16* __restrict__ fh,
                 const float* __restrict__ cx2,
                 const float* __restrict__ dataset,
                 float* __restrict__ partial) {
    __shared__ __align__(16) _Float16 xt[BN * DDIM];
    const int tid = threadIdx.x;
    const int lane = tid & 63;
    const int w = tid >> 6;
    const int l15 = lane & 15;
    const int lh = lane >> 4;
    const int qbase = blockIdx.x * 256 + w * 64;
    const int nstart = blockIdx.y * FNPB;
    const int nlimit = min(nstart + FNPB, NCNT);

    half8_t a[4][2];
#pragma unroll
    for (int qt = 0; qt < 4; ++qt)
#pragma unroll
        for (int kt = 0; kt < 2; ++kt)
            a[qt][kt] = *(const half8_t*)(fh + (size_t)(qbase + qt * 16 + l15) * DDIM
                                             + kt * 32 + lh * 8);
    float sum[4][4];
#pragma unroll
    for (int qt = 0; qt < 4; ++qt)
#pragma unroll
        for (int r = 0; r < 4; ++r) sum[qt][r] = 0.f;

    const int sn = tid >> 2;
    const int sk = tid & 3;
    const int c0 = (sk * 2) ^ (sn & 7);
    const int c1 = (sk * 2 + 1) ^ (sn & 7);

    for (int it = 0; it < FNITERS; ++it) {
        const int nb = nstart + it * BN;
        __syncthreads();
        {
            const int ng = nb + sn;
            float4_t v0 = {0.f,0.f,0.f,0.f}, v1 = {0.f,0.f,0.f,0.f};
            float4_t v2 = {0.f,0.f,0.f,0.f}, v3 = {0.f,0.f,0.f,0.f};
            if (ng < nlimit) {
                const float4_t* src = (const float4_t*)(dataset + (size_t)ng * DDIM + sk * 16);
                v0 = src[0]; v1 = src[1]; v2 = src[2]; v3 = src[3];
            }
            half8_t h0, h1;
            h0[0]=(_Float16)v0[0]; h0[1]=(_Float16)v0[1]; h0[2]=(_Float16)v0[2]; h0[3]=(_Float16)v0[3];
            h0[4]=(_Float16)v1[0]; h0[5]=(_Float16)v1[1]; h0[6]=(_Float16)v1[2]; h0[7]=(_Float16)v1[3];
            h1[0]=(_Float16)v2[0]; h1[1]=(_Float16)v2[1]; h1[2]=(_Float16)v2[2]; h1[3]=(_Float16)v2[3];
            h1[4]=(_Float16)v3[0]; h1[5]=(_Float16)v3[1]; h1[6]=(_Float16)v3[2]; h1[7]=(_Float16)v3[3];
            *(half8_t*)(xt + sn * DDIM + c0 * 8) = h0;
            *(half8_t*)(xt + sn * DDIM + c1 * 8) = h1;
        }
        __syncthreads();
#pragma unroll
        for (int nt = 0; nt < 4; ++nt) {
            const int ng = nb + nt * 16 + l15;
            const float c2 = (ng < nlimit) ? cx2[ng] : -1.0e30f;
            const int brow = nt * 16 + l15;
            const half8_t b0 = *(const half8_t*)(xt + brow * DDIM + ((lh ^ (brow & 7)) * 8));
            const half8_t b1 = *(const half8_t*)(xt + brow * DDIM + (((4 + lh) ^ (brow & 7)) * 8));
#pragma unroll
            for (int qt = 0; qt < 4; ++qt) {
                float4_t c = {c2, c2, c2, c2};
                float4_t acc = __builtin_amdgcn_mfma_f32_16x16x32_f16(a[qt][0], b0, c, 0, 0, 0);
                acc = __builtin_amdgcn_mfma_f32_16x16x32_f16(a[qt][1], b1, acc, 0, 0, 0);
#pragma unroll
                for (int r = 0; r < 4; ++r)
                    sum[qt][r] += __builtin_amdgcn_exp2f(acc[r]);
            }
        }
    }
#pragma unroll
    for (int qt = 0; qt < 4; ++qt)
#pragma unroll
        for (int r = 0; r < 4; ++r) {
            float s = sum[qt][r];
            s += __shfl_xor(s, 1, 64);
            s += __shfl_xor(s, 2, 64);
            s += __shfl_xor(s, 4, 64);
            s += __shfl_xor(s, 8, 64);
            sum[qt][r] = s;
        }
    if (l15 == 0) {
        float* dst = partial + (size_t)blockIdx.y * QCNT + qbase;
#pragma unroll
        for (int qt = 0; qt < 4; ++qt)
#pragma unroll
            for (int r = 0; r < 4; ++r)
                dst[qt * 16 + lh * 4 + r] = sum[qt][r];
    }
}

// ---- final: out[q] = (sum_sp partial) * exp2(cf2[q]) * norm / N ---------
// 4 threads per q (64 blocks) -> latency-hiding for the tail reduction
__global__ void reduce_kernel(const float* __restrict__ partial,
                              const float* __restrict__ cf2,
                              const float* __restrict__ norm,
                              float* __restrict__ out, int splits) {
    const int t = blockIdx.x * blockDim.x + threadIdx.x;  // 0..16383
    const int q = t >> 2;
    const int sub = t & 3;
    if (q >= QCNT) return;
    const int per = splits >> 2;
    float s = 0.f;
    for (int sp = sub * per; sp < (sub + 1) * per; ++sp)
        s += partial[(size_t)sp * QCNT + q];
    s += __shfl_xor(s, 1, 64);
    s += __shfl_xor(s, 2, 64);
    if (sub == 0)
        out[q] = s * __builtin_amdgcn_exp2f(cf2[q]) * norm[0] * (1.0f / (float)NCNT);
}

extern "C" void kernel_launch(void* const* d_in, const int* in_sizes, int n_in,
                              void* d_out, int out_size, void* d_ws, size_t ws_size,
                              hipStream_t stream) {
    const float* features = (const float*)d_in[0];
    const float* bw       = (const float*)d_in[1];
    const float* dataset  = (const float*)d_in[2];
    const float* norm     = (const float*)d_in[3];
    float* out = (float*)d_out;
    float* ws = (float*)d_ws;

    // fast-path ws layout (floats): xhp 1703936 | fh 131072 | cf2 4096 |
    // ecxg 53248 | partial 262144  => 8.62 MB
    const size_t NEED = (size_t)(1703936 + 131072 + 4096 + 53248 + 262144) * 4;

    if (ws_size >= NEED) {
        _Float16* xhp = (_Float16*)ws;
        _Float16* fh  = (_Float16*)(ws + 1703936);
        float* cf2     = ws + 1703936 + 131072;
        float* ecxg    = cf2 + 4096;
        float* partial = ecxg + 53248;

        prep_fused<<<PREP_F_BLOCKS + PREP_X_BLOCKS, 256, 0, stream>>>(
            features, bw, dataset, fh, cf2, xhp, ecxg);
        kde_main_fast<<<QTILES * SPLITS, 512, 0, stream>>>(fh, ecxg, xhp, partial);
        reduce_kernel<<<(QCNT * 4) / 256, 256, 0, stream>>>(partial, cf2, norm, out, SPLITS);
    } else {
        _Float16* fh = (_Float16*)ws;                 // 131072 floats
        float* cf2     = ws + 131072;
        float* cx2     = ws + 131072 + 4096;
        float* partial = ws + 131072 + 4096 + 50176;  // FSPLITS*QCNT

        prep_f_kernel<<<QCNT / 4, 256, 0, stream>>>(features, bw, fh, cf2);
        prep_x2_kernel<<<(NCNT + 255) / 256, 256, 0, stream>>>(dataset, cx2);
        dim3 grid(QCNT / 256, FSPLITS);
        kde_main_fb<<<grid, 256, 0, stream>>>(fh, cx2, dataset, partial);
        reduce_kernel<<<(QCNT * 4) / 256, 256, 0, stream>>>(partial, cf2, norm, out, FSPLITS);
    }
}

// Round 20
// 54.889 us; speedup vs baseline: 5.0770x; 1.0289x over previous
//
#include <hip/hip_runtime.h>

// GaussianKDE via f16 MFMA — FINAL CHAMPION (r14/r16, 54.97us measured):
// r12 geometry (SPLITS=64, 1024 blocks, barrier-free, B direct from L2,
// temporal wave skew) with intra-wave two-stage pipeline (MFMA h+1 || exp2 h).
// CLOSED DEAD ENDS (all counter-confirmed over 19 rounds):
//  - 3rd B buffer / deeper prefetch: allocator spills (r6/r8/r9/r11)
//  - >1024 blocks / higher occupancy: L2 thrash + prologue (r4/r9/r13)
//  - threadfence fused reduction: L2 flush kills xhp residency (r15)
//  - producer/consumer waves: barrier serialization (r17)
//  - grid.sync mega-kernel: cross-XCD coherence flush (r18)
//  - 512-thr spill-free 2-stage: neutral (r19) -> plateau is structural
// estimate[q] = (norm/N) * exp2(cf2_q) * sum_n exp2(dot2(q,n)) * ecx_n
//   dot2 = sum_k (log2e * f_qk) * x_nk   (f16 MFMA, fp32 accum, C=0)
//   cf2  = -0.5*log2e*||f_q||^2 (fp32),  ecx = exp2(-0.5*log2e*||x_n||^2)
// xhp is f16 in MFMA-FRAGMENT ORDER; one HALF-unit = 16 rows = 1024 halves =
// 2 coalesced 1KB dwordx4 loads per wave. Per-XCD working set 852 KB -> L2.

#define QCNT 4096
#define NCNT 50000
#define DDIM 64

// fast path (r12 geometry)
#define SPLITS 64
#define NPB 832             // 13*64; SPLITS*NPB = 53248 >= 50000 (padded)
#define NROWS (SPLITS * NPB)
#define NHALVES 52          // half-units of 16 rows per split
#define QTILES (QCNT / 256) // 16
#define SPLIT_HALVES (NPB * DDIM)   // 53248 f16 per split slice

// fallback (round-2 proven path)
#define FSPLITS 32
#define FNPB 1563
#define FNITERS 25
#define BN 64

typedef _Float16 half8_t __attribute__((ext_vector_type(8)));
typedef float float4_t __attribute__((ext_vector_type(4)));

#define K2F 1.44269504088896340f   // log2(e)
#define KC2 -0.72134752044448169f  // -0.5*log2(e)

// ---- fused prep: blocks [0,1024) do f-prep; [1024, 2688) do x-prep ------
#define PREP_F_BLOCKS (QCNT / 4)            // 1024
#define PREP_X_BLOCKS (NROWS * 8 / 256)     // 1664

__global__ void prep_fused(const float* __restrict__ features,
                           const float* __restrict__ bw,
                           const float* __restrict__ dataset,
                           _Float16* __restrict__ fh,
                           float* __restrict__ cf2,
                           _Float16* __restrict__ xhp,
                           float* __restrict__ ecxg) {
    if (blockIdx.x < PREP_F_BLOCKS) {
        // f = features@bw; fh = f16(K2*f); cf2 = KC2*||f||^2  (1 wave / q-row)
        const int lane = threadIdx.x & 63;
        const int q = blockIdx.x * 4 + (threadIdx.x >> 6);
        const float* frow = features + q * DDIM;
        float acc = 0.f;
#pragma unroll
        for (int k = 0; k < DDIM; ++k)
            acc = fmaf(frow[k], bw[k * DDIM + lane], acc);
        fh[(size_t)q * DDIM + lane] = (_Float16)(K2F * acc);
        float s = acc * acc;
#pragma unroll
        for (int m = 1; m < 64; m <<= 1) s += __shfl_xor(s, m, 64);
        if (lane == 0) cf2[q] = KC2 * s;
    } else {
        // xhp = f16 dataset in MFMA-fragment order; ecxg = exp2(KC2*||x||^2)
        const int t = (blockIdx.x - PREP_F_BLOCKS) * 256 + threadIdx.x;
        const int row = t >> 3;
        const int c = t & 7;                  // 8-half chunk = k [c*8, c*8+8)
        if (row >= NROWS) return;
        float4_t v0 = {0.f, 0.f, 0.f, 0.f}, v1 = {0.f, 0.f, 0.f, 0.f};
        if (row < NCNT) {
            const float4_t* src = (const float4_t*)(dataset + (size_t)row * DDIM + c * 8);
            v0 = src[0]; v1 = src[1];
        }
        float s = v0[0]*v0[0] + v0[1]*v0[1] + v0[2]*v0[2] + v0[3]*v0[3]
                + v1[0]*v1[0] + v1[1]*v1[1] + v1[2]*v1[2] + v1[3]*v1[3];
        s += __shfl_xor(s, 1, 64);
        s += __shfl_xor(s, 2, 64);
        s += __shfl_xor(s, 4, 64);
        if (c == 0) ecxg[row] = (row < NCNT) ? __builtin_amdgcn_exp2f(KC2 * s) : 0.f;
        half8_t h;
        h[0] = (_Float16)v0[0]; h[1] = (_Float16)v0[1];
        h[2] = (_Float16)v0[2]; h[3] = (_Float16)v0[3];
        h[4] = (_Float16)v1[0]; h[5] = (_Float16)v1[1];
        h[6] = (_Float16)v1[2]; h[7] = (_Float16)v1[3];
        // fragment-order address: row -> (split, half hh, l15); c -> (f, lh)
        const int split = row / NPB;
        const int nr = row - split * NPB;
        const int hh = nr >> 4;               // half-unit 0..51 (16 rows)
        const int l15 = nr & 15;
        const int f = c >> 2;
        const int lh = c & 3;
        const int lane = lh * 16 + l15;
        const size_t base = (((size_t)split * NHALVES + hh) * 2 + f) * 512;
        *(half8_t*)(xhp + base + lane * 8) = h;
    }
}

// ---- main (fast): intra-wave 2-stage pipeline (MFMA h+1 || exp2 h) ------
__global__ __attribute__((amdgpu_flat_work_group_size(256, 256),
                          amdgpu_waves_per_eu(4, 4)))
void kde_main_fast(const _Float16* __restrict__ fh,
                   const float* __restrict__ ecxg,
                   const _Float16* __restrict__ xhp,
                   float* __restrict__ partial) {
    __shared__ float lecx[NPB];             // 3.25 KB, read-only after init

    const int tid = threadIdx.x;
    const int lane = tid & 63;
    const int w = tid >> 6;
    const int l15 = lane & 15;
    const int lh = lane >> 4;

    // bijective XCD swizzle (r3-proven): 1024 = 8 xcd x 8 splits x 16 qtiles
    const int bid = blockIdx.x;
    const int xcd = bid & 7;
    const int j = bid >> 3;                 // 0..127
    const int split = xcd * 8 + (j & 7);    // 0..63
    const int qtile = j >> 3;               // 0..15

    const int qbase = qtile * 256 + w * 64; // wave owns 64 q-rows

    // A fragments resident in VGPRs: lane l -> row qt*16+l15, k = kt*32+lh*8
    half8_t a[4][2];
#pragma unroll
    for (int qt = 0; qt < 4; ++qt)
#pragma unroll
        for (int kt = 0; kt < 2; ++kt)
            a[qt][kt] = *(const half8_t*)(fh + (size_t)(qbase + qt * 16 + l15) * DDIM
                                             + kt * 32 + lh * 8);

    // persistent ecx tile for all iterations
    {
        const float* es = ecxg + (size_t)split * NPB;
        for (int i = tid; i < NPB; i += 256) lecx[i] = es[i];
    }
    __syncthreads();                        // only barrier in the kernel

    // TEMPORAL skew: desynchronize co-resident waves (r10-proven, +13%)
    {
        const int skew = w + ((bid >> 3) & 3);   // 0..6
#pragma unroll 1
        for (int i = 0; i < skew; ++i) __builtin_amdgcn_s_sleep(2);
    }

    const _Float16* bs = xhp + (size_t)split * SPLIT_HALVES + (size_t)lane * 8;

    float sum[4][4];
#pragma unroll
    for (int qt = 0; qt < 4; ++qt)
#pragma unroll
        for (int r = 0; r < 4; ++r) sum[qt][r] = 0.f;

    const float4_t zc = {0.f, 0.f, 0.f, 0.f};   // hoisted zero C quad

    // half-unit h: 16 rows = 2 x 1KB coalesced dwordx4
#define LOADH(L, h_)                                                          \
    {                                                                         \
        const _Float16* p_ = bs + (size_t)(h_) * 1024;                        \
        L[0] = *(const half8_t*)(p_);                                         \
        L[1] = *(const half8_t*)(p_ + 512);                                   \
    }

    // 8 back-to-back MFMA into the T quad set (matrix pipe burst)
#define MFMAH(T, L)                                                           \
    {                                                                         \
        __builtin_amdgcn_s_setprio(1);                                        \
        T[0] = __builtin_amdgcn_mfma_f32_16x16x32_f16(a[0][0], L[0], zc, 0, 0, 0); \
        T[1] = __builtin_amdgcn_mfma_f32_16x16x32_f16(a[1][0], L[0], zc, 0, 0, 0); \
        T[2] = __builtin_amdgcn_mfma_f32_16x16x32_f16(a[2][0], L[0], zc, 0, 0, 0); \
        T[3] = __builtin_amdgcn_mfma_f32_16x16x32_f16(a[3][0], L[0], zc, 0, 0, 0); \
        T[0] = __builtin_amdgcn_mfma_f32_16x16x32_f16(a[0][1], L[1], T[0], 0, 0, 0); \
        T[1] = __builtin_amdgcn_mfma_f32_16x16x32_f16(a[1][1], L[1], T[1], 0, 0, 0); \
        T[2] = __builtin_amdgcn_mfma_f32_16x16x32_f16(a[2][1], L[1], T[2], 0, 0, 0); \
        T[3] = __builtin_amdgcn_mfma_f32_16x16x32_f16(a[3][1], L[1], T[3], 0, 0, 0); \
        __builtin_amdgcn_s_setprio(0);                                        \
    }

    // 16 exp2 + 16 fma for half h_ (trans/VALU burst)
#define EXPH(T, h_)                                                           \
    {                                                                         \
        const float e_ = lecx[(h_) * 16 + l15];                               \
        _Pragma("unroll")                                                     \
        for (int r = 0; r < 4; ++r) {                                         \
            sum[0][r] = fmaf(__builtin_amdgcn_exp2f(T[0][r]), e_, sum[0][r]); \
            sum[1][r] = fmaf(__builtin_amdgcn_exp2f(T[1][r]), e_, sum[1][r]); \
            sum[2][r] = fmaf(__builtin_amdgcn_exp2f(T[2][r]), e_, sum[2][r]); \
            sum[3][r] = fmaf(__builtin_amdgcn_exp2f(T[3][r]), e_, sum[3][r]); \
        }                                                                     \
    }

    half8_t lA[2], lB[2];                   // 8 + 8 VGPRs
    float4_t tA[4], tB[4];                  // 16 + 16 VGPRs

    // prologue: establish invariant {tA = MFMA(h), lB = h+1, lA = h+2}
    LOADH(lA, 0);
    LOADH(lB, 1);
    MFMAH(tA, lA);                          // half 0
    LOADH(lA, 2);

#pragma unroll 1
    for (int h = 0; h < NHALVES - 4; h += 2) {   // h = 0,2,...,46
        MFMAH(tB, lB);                      // half h+1 -> matrix pipe busy
        EXPH(tA, h);                        // half h   -> trans pipe busy
        LOADH(lB, h + 3);
        MFMAH(tA, lA);                      // half h+2
        EXPH(tB, h + 1);
        LOADH(lA, h + 4);
    }
    // exit invariant: tA = MFMA(48), lB = half 49, lA = half 50
    MFMAH(tB, lB);                          // half 49
    EXPH(tA, 48);
    LOADH(lB, 51);
    MFMAH(tA, lA);                          // half 50
    EXPH(tB, 49);
    MFMAH(tB, lB);                          // half 51
    EXPH(tA, 50);
    EXPH(tB, 51);

    // reduce over the 16 n-columns (lanes within each lh group)
#pragma unroll
    for (int qt = 0; qt < 4; ++qt)
#pragma unroll
        for (int r = 0; r < 4; ++r) {
            float s = sum[qt][r];
            s += __shfl_xor(s, 1, 64);
            s += __shfl_xor(s, 2, 64);
            s += __shfl_xor(s, 4, 64);
            s += __shfl_xor(s, 8, 64);
            sum[qt][r] = s;
        }
    if (l15 == 0) {
        float* dst = partial + (size_t)split * QCNT + qbase;
#pragma unroll
        for (int qt = 0; qt < 4; ++qt)
#pragma unroll
            for (int r = 0; r < 4; ++r)
                dst[qt * 16 + lh * 4 + r] = sum[qt][r];   // C row = lh*4 + r
    }
#undef LOADH
#undef MFMAH
#undef EXPH
}

// ======================= fallback path (round-2, proven) ==================
__global__ void prep_f_kernel(const float* __restrict__ features,
                              const float* __restrict__ bw,
                              _Float16* __restrict__ fh,
                              float* __restrict__ cf2) {
    const int lane = threadIdx.x & 63;
    const int q = blockIdx.x * (blockDim.x >> 6) + (threadIdx.x >> 6);
    if (q >= QCNT) return;
    const float* frow = features + q * DDIM;
    float acc = 0.f;
#pragma unroll
    for (int k = 0; k < DDIM; ++k)
        acc = fmaf(frow[k], bw[k * DDIM + lane], acc);
    fh[(size_t)q * DDIM + lane] = (_Float16)(K2F * acc);
    float s = acc * acc;
#pragma unroll
    for (int m = 1; m < 64; m <<= 1) s += __shfl_xor(s, m, 64);
    if (lane == 0) cf2[q] = KC2 * s;
}

__global__ void prep_x2_kernel(const float* __restrict__ dataset,
                               float* __restrict__ cx2) {
    const int n = blockIdx.x * blockDim.x + threadIdx.x;
    if (n >= NCNT) return;
    const float4* row = (const float4*)(dataset + (size_t)n * DDIM);
    float s = 0.f;
#pragma unroll
    for (int jq = 0; jq < DDIM / 4; ++jq) {
        float4 v = row[jq];
        s += v.x * v.x + v.y * v.y + v.z * v.z + v.w * v.w;
    }
    cx2[n] = KC2 * s;
}

__global__ __launch_bounds__(256, 2)
void kde_main_fb(const _Float16* __restrict__ fh,
                 const float* __restrict__ cx2,
                 const float* __restrict__ dataset,
                 float* __restrict__ partial) {
    __shared__ __align__(16) _Float16 xt[BN * DDIM];
    const int tid = threadIdx.x;
    const int lane = tid & 63;
    const int w = tid >> 6;
    const int l15 = lane & 15;
    const int lh = lane >> 4;
    const int qbase = blockIdx.x * 256 + w * 64;
    const int nstart = blockIdx.y * FNPB;
    const int nlimit = min(nstart + FNPB, NCNT);

    half8_t a[4][2];
#pragma unroll
    for (int qt = 0; qt < 4; ++qt)
#pragma unroll
        for (int kt = 0; kt < 2; ++kt)
            a[qt][kt] = *(const half8_t*)(fh + (size_t)(qbase + qt * 16 + l15) * DDIM
                                             + kt * 32 + lh * 8);
    float sum[4][4];
#pragma unroll
    for (int qt = 0; qt < 4; ++qt)
#pragma unroll
        for (int r = 0; r < 4; ++r) sum[qt][r] = 0.f;

    const int sn = tid >> 2;
    const int sk = tid & 3;
    const int c0 = (sk * 2) ^ (sn & 7);
    const int c1 = (sk * 2 + 1) ^ (sn & 7);

    for (int it = 0; it < FNITERS; ++it) {
        const int nb = nstart + it * BN;
        __syncthreads();
        {
            const int ng = nb + sn;
            float4_t v0 = {0.f,0.f,0.f,0.f}, v1 = {0.f,0.f,0.f,0.f};
            float4_t v2 = {0.f,0.f,0.f,0.f}, v3 = {0.f,0.f,0.f,0.f};
            if (ng < nlimit) {
                const float4_t* src = (const float4_t*)(dataset + (size_t)ng * DDIM + sk * 16);
                v0 = src[0]; v1 = src[1]; v2 = src[2]; v3 = src[3];
            }
            half8_t h0, h1;
            h0[0]=(_Float16)v0[0]; h0[1]=(_Float16)v0[1]; h0[2]=(_Float16)v0[2]; h0[3]=(_Float16)v0[3];
            h0[4]=(_Float16)v1[0]; h0[5]=(_Float16)v1[1]; h0[6]=(_Float16)v1[2]; h0[7]=(_Float16)v1[3];
            h1[0]=(_Float16)v2[0]; h1[1]=(_Float16)v2[1]; h1[2]=(_Float16)v2[2]; h1[3]=(_Float16)v2[3];
            h1[4]=(_Float16)v3[0]; h1[5]=(_Float16)v3[1]; h1[6]=(_Float16)v3[2]; h1[7]=(_Float16)v3[3];
            *(half8_t*)(xt + sn * DDIM + c0 * 8) = h0;
            *(half8_t*)(xt + sn * DDIM + c1 * 8) = h1;
        }
        __syncthreads();
#pragma unroll
        for (int nt = 0; nt < 4; ++nt) {
            const int ng = nb + nt * 16 + l15;
            const float c2 = (ng < nlimit) ? cx2[ng] : -1.0e30f;
            const int brow = nt * 16 + l15;
            const half8_t b0 = *(const half8_t*)(xt + brow * DDIM + ((lh ^ (brow & 7)) * 8));
            const half8_t b1 = *(const half8_t*)(xt + brow * DDIM + (((4 + lh) ^ (brow & 7)) * 8));
#pragma unroll
            for (int qt = 0; qt < 4; ++qt) {
                float4_t c = {c2, c2, c2, c2};
                float4_t acc = __builtin_amdgcn_mfma_f32_16x16x32_f16(a[qt][0], b0, c, 0, 0, 0);
                acc = __builtin_amdgcn_mfma_f32_16x16x32_f16(a[qt][1], b1, acc, 0, 0, 0);
#pragma unroll
                for (int r = 0; r < 4; ++r)
                    sum[qt][r] += __builtin_amdgcn_exp2f(acc[r]);
            }
        }
    }
#pragma unroll
    for (int qt = 0; qt < 4; ++qt)
#pragma unroll
        for (int r = 0; r < 4; ++r) {
            float s = sum[qt][r];
            s += __shfl_xor(s, 1, 64);
            s += __shfl_xor(s, 2, 64);
            s += __shfl_xor(s, 4, 64);
            s += __shfl_xor(s, 8, 64);
            sum[qt][r] = s;
        }
    if (l15 == 0) {
        float* dst = partial + (size_t)blockIdx.y * QCNT + qbase;
#pragma unroll
        for (int qt = 0; qt < 4; ++qt)
#pragma unroll
            for (int r = 0; r < 4; ++r)
                dst[qt * 16 + lh * 4 + r] = sum[qt][r];
    }
}

// ---- final: out[q] = (sum_sp partial) * exp2(cf2[q]) * norm / N ---------
// 4 threads per q (64 blocks) -> latency-hiding for the tail reduction
__global__ void reduce_kernel(const float* __restrict__ partial,
                              const float* __restrict__ cf2,
                              const float* __restrict__ norm,
                              float* __restrict__ out, int splits) {
    const int t = blockIdx.x * blockDim.x + threadIdx.x;  // 0..16383
    const int q = t >> 2;
    const int sub = t & 3;
    if (q >= QCNT) return;
    const int per = splits >> 2;
    float s = 0.f;
    for (int sp = sub * per; sp < (sub + 1) * per; ++sp)
        s += partial[(size_t)sp * QCNT + q];
    s += __shfl_xor(s, 1, 64);
    s += __shfl_xor(s, 2, 64);
    if (sub == 0)
        out[q] = s * __builtin_amdgcn_exp2f(cf2[q]) * norm[0] * (1.0f / (float)NCNT);
}

extern "C" void kernel_launch(void* const* d_in, const int* in_sizes, int n_in,
                              void* d_out, int out_size, void* d_ws, size_t ws_size,
                              hipStream_t stream) {
    const float* features = (const float*)d_in[0];
    const float* bw       = (const float*)d_in[1];
    const float* dataset  = (const float*)d_in[2];
    const float* norm     = (const float*)d_in[3];
    float* out = (float*)d_out;
    float* ws = (float*)d_ws;

    // fast-path ws layout (floats): xhp 1703936 | fh 131072 | cf2 4096 |
    // ecxg 53248 | partial 262144  => 8.62 MB
    const size_t NEED = (size_t)(1703936 + 131072 + 4096 + 53248 + 262144) * 4;

    if (ws_size >= NEED) {
        _Float16* xhp = (_Float16*)ws;
        _Float16* fh  = (_Float16*)(ws + 1703936);
        float* cf2     = ws + 1703936 + 131072;
        float* ecxg    = cf2 + 4096;
        float* partial = ecxg + 53248;

        prep_fused<<<PREP_F_BLOCKS + PREP_X_BLOCKS, 256, 0, stream>>>(
            features, bw, dataset, fh, cf2, xhp, ecxg);
        kde_main_fast<<<QTILES * SPLITS, 256, 0, stream>>>(fh, ecxg, xhp, partial);
        reduce_kernel<<<(QCNT * 4) / 256, 256, 0, stream>>>(partial, cf2, norm, out, SPLITS);
    } else {
        _Float16* fh = (_Float16*)ws;                 // 131072 floats
        float* cf2     = ws + 131072;
        float* cx2     = ws + 131072 + 4096;
        float* partial = ws + 131072 + 4096 + 50176;  // FSPLITS*QCNT

        prep_f_kernel<<<QCNT / 4, 256, 0, stream>>>(features, bw, fh, cf2);
        prep_x2_kernel<<<(NCNT + 255) / 256, 256, 0, stream>>>(dataset, cx2);
        dim3 grid(QCNT / 256, FSPLITS);
        kde_main_fb<<<grid, 256, 0, stream>>>(fh, cx2, dataset, partial);
        reduce_kernel<<<(QCNT * 4) / 256, 256, 0, stream>>>(partial, cf2, norm, out, FSPLITS);
    }
}